// Round 10
// baseline (465.143 us; speedup 1.0000x reference)
//
#include <hip/hip_runtime.h>
#include <hip/hip_bf16.h>
#include <stdint.h>

typedef _Float16 f16x8 __attribute__((ext_vector_type(8)));
typedef _Float16 f16x2 __attribute__((ext_vector_type(2)));
typedef float f32x4 __attribute__((ext_vector_type(4)));

#define AL 136   // LDS leading dim for 128-wide fp16 tiles (+8 pad)

// ------------- weight prep: f32 [i][o] 128x128 tile -> fp16 dst[o*stride + i] -------------
struct PrepDesc { const float* src; _Float16* dst; int dstride; };
struct PrepArgs { PrepDesc d[33]; };

__global__ __launch_bounds__(256) void prep_weights(PrepArgs args) {
    __shared__ _Float16 lds[128 * 129];
    const PrepDesc de = args.d[blockIdx.x];
    int t = threadIdx.x;
    for (int q = 0; q < 64; ++q) {
        int li = t + q * 256;            // linear over src [i][o]
        int i = li >> 7, o = li & 127;
        lds[o * 129 + i] = (_Float16)de.src[li];
    }
    __syncthreads();
    for (int q = 0; q < 64; ++q) {
        int lo = t + q * 256;            // linear over dst [o][i]
        int o = lo >> 7, i = lo & 127;
        de.dst[(size_t)o * de.dstride + i] = lds[o * 129 + i];
    }
}

// ---------------- f32 -> fp16 convert ----------------
__global__ __launch_bounds__(256) void f32_to_f16(const float* __restrict__ in,
                                                  _Float16* __restrict__ out, int n4) {
    int i = blockIdx.x * 256 + threadIdx.x;
    if (i >= n4) return;
    float4 v = *((const float4*)in + i);
    f16x2 a, b;
    a[0] = (_Float16)v.x; a[1] = (_Float16)v.y;
    b[0] = (_Float16)v.z; b[1] = (_Float16)v.w;
    f16x2* o = (f16x2*)out + i * 2;
    o[0] = a; o[1] = b;
}

// ---------------- CSR build (3 views concatenated: index space [3][N]) ----------------
struct EdgeArgs {
    const int* src[3]; const int* dst[3]; const int* rel[3];
    int E[3]; int N;
};

__global__ __launch_bounds__(256) void zero_deg(int* __restrict__ deg3, int n) {
    int i = blockIdx.x * 256 + threadIdx.x;
    if (i < n) deg3[i] = 0;
}

__global__ __launch_bounds__(256) void hist3(EdgeArgs ea, int* __restrict__ deg3) {
    int v = blockIdx.y;
    const int* dst = ea.dst[v];
    int* deg = deg3 + (size_t)v * ea.N;
    for (int e = blockIdx.x * 256 + threadIdx.x; e < ea.E[v]; e += gridDim.x * 256)
        atomicAdd(&deg[dst[e]], 1);
}

__global__ __launch_bounds__(256) void scan1_kernel(const int* __restrict__ deg,
                                                    int* __restrict__ off,
                                                    int* __restrict__ bsum, int n) {
    __shared__ int s[256];
    int b = blockIdx.x, t = threadIdx.x;
    int base = b * 2048 + t * 8;
    int v[8]; int sum = 0;
    for (int j = 0; j < 8; ++j) {
        int x = (base + j < n) ? deg[base + j] : 0;
        v[j] = sum;
        sum += x;
    }
    s[t] = sum;
    __syncthreads();
    for (int st = 1; st < 256; st <<= 1) {
        int y = (t >= st) ? s[t - st] : 0;
        __syncthreads();
        s[t] += y;
        __syncthreads();
    }
    int texcl = t ? s[t - 1] : 0;
    if (t == 255) bsum[b] = s[255];
    for (int j = 0; j < 8; ++j)
        if (base + j < n) off[base + j] = texcl + v[j];
}

__global__ __launch_bounds__(256) void scan2_kernel(int* __restrict__ off,
                                                    int* __restrict__ cur,
                                                    const int* __restrict__ bsum,
                                                    int n, int Etot) {
    __shared__ int pref;
    int b = blockIdx.x, t = threadIdx.x;
    if (t == 0) { int p = 0; for (int j = 0; j < b; ++j) p += bsum[j]; pref = p; }
    __syncthreads();
    int p = pref;
    int base = b * 2048 + t * 8;
    for (int j = 0; j < 8; ++j)
        if (base + j < n) { int x = off[base + j] + p; off[base + j] = x; cur[base + j] = x; }
    if (b == 0 && t == 0) off[n] = Etot;
}

__global__ __launch_bounds__(256) void scatter3(EdgeArgs ea, int* __restrict__ cur3,
                                                int* __restrict__ packed3) {
    int v = blockIdx.y;
    const int* src = ea.src[v];
    const int* dst = ea.dst[v];
    const int* rel = ea.rel[v];
    int* cur = cur3 + (size_t)v * ea.N;
    for (int e = blockIdx.x * 256 + threadIdx.x; e < ea.E[v]; e += gridDim.x * 256) {
        int pos = atomicAdd(&cur[dst[e]], 1);
        packed3[pos] = src[e] | (rel[e] << 20);
    }
}

// ---- gather: T[v][d][b][:] = sum_{e->d} coef_v[rel_e][b] * h_v[src_e][:], one wave/node ----
struct GatherArgs {
    const int* off3;
    const int* packed3;
    const float* coef[3];     // [R][4]
    const _Float16* h[3];     // [N][128] per-view input
    _Float16* T;              // output base
    int N; size_t Tvs;
};

__global__ __launch_bounds__(256) void gather3(GatherArgs g) {
    int v = blockIdx.y;
    int node = (blockIdx.x << 2) | (threadIdx.x >> 6);
    if (node >= g.N) return;
    int lane = threadIdx.x & 63;
    const int* off = g.off3 + (size_t)v * g.N;
    const float* coef = g.coef[v];
    const _Float16* h = g.h[v];
    _Float16* T = g.T + (size_t)v * g.Tvs;

    int i  = __builtin_amdgcn_readfirstlane(off[node]);
    int e1 = __builtin_amdgcn_readfirstlane(off[node + 1]);
    float acc[8] = {};   // [b][2]

    for (; i + 3 < e1; i += 4) {
        int p0 = __builtin_amdgcn_readfirstlane(g.packed3[i]);
        int p1 = __builtin_amdgcn_readfirstlane(g.packed3[i + 1]);
        int p2 = __builtin_amdgcn_readfirstlane(g.packed3[i + 2]);
        int p3 = __builtin_amdgcn_readfirstlane(g.packed3[i + 3]);
        int s0 = p0 & 0xFFFFF, r0 = p0 >> 20;
        int s1 = p1 & 0xFFFFF, r1 = p1 >> 20;
        int s2 = p2 & 0xFFFFF, r2 = p2 >> 20;
        int s3 = p3 & 0xFFFFF, r3 = p3 >> 20;
        uint32_t q0 = ((const uint32_t*)(h + (size_t)s0 * 128))[lane];
        uint32_t q1 = ((const uint32_t*)(h + (size_t)s1 * 128))[lane];
        uint32_t q2 = ((const uint32_t*)(h + (size_t)s2 * 128))[lane];
        uint32_t q3 = ((const uint32_t*)(h + (size_t)s3 * 128))[lane];
        float4 c0 = *(const float4*)(coef + (size_t)r0 * 4);
        float4 c1 = *(const float4*)(coef + (size_t)r1 * 4);
        float4 c2 = *(const float4*)(coef + (size_t)r2 * 4);
        float4 c3 = *(const float4*)(coef + (size_t)r3 * 4);
        f16x2 u0 = __builtin_bit_cast(f16x2, q0);
        f16x2 u1 = __builtin_bit_cast(f16x2, q1);
        f16x2 u2 = __builtin_bit_cast(f16x2, q2);
        f16x2 u3 = __builtin_bit_cast(f16x2, q3);
        float lo0 = (float)u0[0], hi0 = (float)u0[1];
        float lo1 = (float)u1[0], hi1 = (float)u1[1];
        float lo2 = (float)u2[0], hi2 = (float)u2[1];
        float lo3 = (float)u3[0], hi3 = (float)u3[1];
        acc[0] += c0.x * lo0 + c1.x * lo1 + c2.x * lo2 + c3.x * lo3;
        acc[1] += c0.x * hi0 + c1.x * hi1 + c2.x * hi2 + c3.x * hi3;
        acc[2] += c0.y * lo0 + c1.y * lo1 + c2.y * lo2 + c3.y * lo3;
        acc[3] += c0.y * hi0 + c1.y * hi1 + c2.y * hi2 + c3.y * hi3;
        acc[4] += c0.z * lo0 + c1.z * lo1 + c2.z * lo2 + c3.z * lo3;
        acc[5] += c0.z * hi0 + c1.z * hi1 + c2.z * hi2 + c3.z * hi3;
        acc[6] += c0.w * lo0 + c1.w * lo1 + c2.w * lo2 + c3.w * lo3;
        acc[7] += c0.w * hi0 + c1.w * hi1 + c2.w * hi2 + c3.w * hi3;
    }
    for (; i < e1; ++i) {
        int p0 = __builtin_amdgcn_readfirstlane(g.packed3[i]);
        int s0 = p0 & 0xFFFFF, r0 = p0 >> 20;
        uint32_t q0 = ((const uint32_t*)(h + (size_t)s0 * 128))[lane];
        float4 c0 = *(const float4*)(coef + (size_t)r0 * 4);
        f16x2 u0 = __builtin_bit_cast(f16x2, q0);
        float lo0 = (float)u0[0], hi0 = (float)u0[1];
        acc[0] += c0.x * lo0;  acc[1] += c0.x * hi0;
        acc[2] += c0.y * lo0;  acc[3] += c0.y * hi0;
        acc[4] += c0.z * lo0;  acc[5] += c0.z * hi0;
        acc[6] += c0.w * lo0;  acc[7] += c0.w * hi0;
    }
    _Float16* tb = T + (size_t)node * 512 + 2 * lane;
    for (int b = 0; b < 4; ++b) {
        f16x2 o; o[0] = (_Float16)acc[2 * b]; o[1] = (_Float16)acc[2 * b + 1];
        *(f16x2*)(tb + b * 128) = o;
    }
}

// ---- layer GEMM v3: out = [T | h] @ BT^T + bias (+relu), K=640 ----
// A-fragments DIRECT from global (each row read once, no LDS reuse to exploit);
// only B chunk in LDS (34.8 KB) -> up to 4 blocks/CU. 512 thr, 8 waves (2M x 4N).
struct GemmArgs {
    const _Float16* T;        // base; +v*Tvs
    const _Float16* hin[3];
    const _Float16* WT[3];    // [128][640]
    const float* bias[3];
    _Float16* hout;           // base; +v*hovs
    int M; int relu; size_t Tvs; size_t hovs;
};

__global__ __launch_bounds__(512, 6) void gemm_layer(GemmArgs ga) {
    __shared__ _Float16 Bs[128 * AL];
    int v = blockIdx.y;
    const _Float16* Tb  = ga.T + (size_t)v * ga.Tvs;
    const _Float16* hin = ga.hin[v];
    const _Float16* BT  = ga.WT[v];
    const float* bias   = ga.bias[v];
    _Float16* out       = ga.hout + (size_t)v * ga.hovs;
    int M = ga.M;

    int tid = threadIdx.x;
    int m0 = blockIdx.x * 128;
    int wid = tid >> 6, lane = tid & 63;
    int wr = (wid >> 2) * 64;     // 2 row groups of 64
    int wc = (wid & 3) * 32;      // 4 col groups of 32
    int lm = lane & 15;
    int lk = (lane >> 4) * 8;

    // row indices for this lane's A-fragments (clamped once)
    int gri[4];
    for (int mi = 0; mi < 4; ++mi) {
        int gr = m0 + wr + mi * 16 + lm;
        gri[mi] = gr < M ? gr : M - 1;
    }

    f32x4 acc[4][2] = {};

    for (int kb = 0; kb < 5; ++kb) {
        const _Float16* Asrc; size_t astride;
        if (kb < 4) { Asrc = Tb + (size_t)kb * 128; astride = 512; }
        else        { Asrc = hin;                   astride = 128; }
        const _Float16* ap0 = Asrc + (size_t)gri[0] * astride + lk;
        const _Float16* ap1 = Asrc + (size_t)gri[1] * astride + lk;
        const _Float16* ap2 = Asrc + (size_t)gri[2] * astride + lk;
        const _Float16* ap3 = Asrc + (size_t)gri[3] * astride + lk;

        for (int q = 0; q < 4; ++q) {
            int li = tid + q * 512;
            int r = li >> 4;
            int c = (li & 15) << 3;
            *(f16x8*)(Bs + r * AL + c) = *(const f16x8*)(BT + (size_t)r * 640 + kb * 128 + c);
        }
        __syncthreads();

        for (int ks = 0; ks < 4; ++ks) {
            f16x8 a[4], b[2];
            a[0] = *(const f16x8*)(ap0 + ks * 32);
            a[1] = *(const f16x8*)(ap1 + ks * 32);
            a[2] = *(const f16x8*)(ap2 + ks * 32);
            a[3] = *(const f16x8*)(ap3 + ks * 32);
            for (int ni = 0; ni < 2; ++ni)
                b[ni] = *(const f16x8*)(Bs + (wc + ni * 16 + lm) * AL + ks * 32 + lk);
            for (int mi = 0; mi < 4; ++mi)
                for (int ni = 0; ni < 2; ++ni)
                    acc[mi][ni] = __builtin_amdgcn_mfma_f32_16x16x32_f16(a[mi], b[ni], acc[mi][ni], 0, 0, 0);
        }
        __syncthreads();
    }

    int rbase = (lane >> 4) * 4;
    for (int mi = 0; mi < 4; ++mi) {
        for (int j = 0; j < 4; ++j) {
            int gr = m0 + wr + mi * 16 + rbase + j;
            if (gr >= M) continue;
            for (int ni = 0; ni < 2; ++ni) {
                int col = wc + ni * 16 + lm;
                float val = acc[mi][ni][j] + bias[col];
                if (ga.relu) val = fmaxf(val, 0.f);
                out[(size_t)gr * 128 + col] = (_Float16)val;
            }
        }
    }
}

// ---- fusion GEMM: out_f32 = sum_kb A[kb] @ BT_chunk + bias, BM=128 ----
struct FusArgs {
    const _Float16* A[3];     // K-chunks, each [M][128]
    const _Float16* BT;       // [128][384]
    const float* bias;
    float* out; int M;
};

__global__ __launch_bounds__(256) void gemm_fusion(FusArgs fa) {
    __shared__ _Float16 As[128 * AL];
    __shared__ _Float16 Bs[128 * AL];
    int tid = threadIdx.x;
    int m0 = blockIdx.x * 128;
    int M = fa.M;
    int wid = tid >> 6, lane = tid & 63;
    int wr = (wid >> 1) * 64;
    int wc = (wid & 1) * 64;
    int lm = lane & 15;
    int lk = (lane >> 4) * 8;

    f32x4 acc[4][4] = {};

    for (int kb = 0; kb < 3; ++kb) {
        const _Float16* Asrc = fa.A[kb];
        for (int q = 0; q < 8; ++q) {
            int li = tid + q * 256;
            int r = li >> 4;
            int c = (li & 15) << 3;
            int gr = m0 + r; if (gr >= M) gr = M - 1;
            *(f16x8*)(As + r * AL + c) = *(const f16x8*)(Asrc + (size_t)gr * 128 + c);
        }
        for (int q = 0; q < 8; ++q) {
            int li = tid + q * 256;
            int r = li >> 4;
            int c = (li & 15) << 3;
            *(f16x8*)(Bs + r * AL + c) = *(const f16x8*)(fa.BT + (size_t)r * 384 + kb * 128 + c);
        }
        __syncthreads();

        for (int ks = 0; ks < 4; ++ks) {
            f16x8 a[4], b[4];
            for (int mi = 0; mi < 4; ++mi)
                a[mi] = *(const f16x8*)(As + (wr + mi * 16 + lm) * AL + ks * 32 + lk);
            for (int ni = 0; ni < 4; ++ni)
                b[ni] = *(const f16x8*)(Bs + (wc + ni * 16 + lm) * AL + ks * 32 + lk);
            for (int mi = 0; mi < 4; ++mi)
                for (int ni = 0; ni < 4; ++ni)
                    acc[mi][ni] = __builtin_amdgcn_mfma_f32_16x16x32_f16(a[mi], b[ni], acc[mi][ni], 0, 0, 0);
        }
        __syncthreads();
    }

    int rbase = (lane >> 4) * 4;
    for (int mi = 0; mi < 4; ++mi) {
        for (int j = 0; j < 4; ++j) {
            int gr = m0 + wr + mi * 16 + rbase + j;
            if (gr >= M) continue;
            for (int ni = 0; ni < 4; ++ni) {
                int col = wc + ni * 16 + lm;
                fa.out[(size_t)gr * 128 + col] = acc[mi][ni][j] + fa.bias[col];
            }
        }
    }
}

// ---------------- host launch ----------------
extern "C" void kernel_launch(void* const* d_in, const int* in_sizes, int n_in,
                              void* d_out, int out_size, void* d_ws, size_t ws_size,
                              hipStream_t stream) {
    const int D = 128;
    const int M = in_sizes[0] / D;

    struct ViewIn {
        const int *src, *dst, *rel;
        const float *bases1, *coef1, *loopw1, *bias1;
        const float *bases2, *coef2, *loopw2, *bias2;
        int E;
    } V[3];
    int idx = 1;
    for (int v = 0; v < 3; ++v) {
        V[v].src    = (const int*)d_in[idx + 0];
        V[v].dst    = (const int*)d_in[idx + 1];
        V[v].rel    = (const int*)d_in[idx + 2];
        V[v].bases1 = (const float*)d_in[idx + 3];
        V[v].coef1  = (const float*)d_in[idx + 4];
        V[v].loopw1 = (const float*)d_in[idx + 5];
        V[v].bias1  = (const float*)d_in[idx + 6];
        V[v].bases2 = (const float*)d_in[idx + 7];
        V[v].coef2  = (const float*)d_in[idx + 8];
        V[v].loopw2 = (const float*)d_in[idx + 9];
        V[v].bias2  = (const float*)d_in[idx + 10];
        V[v].E      = in_sizes[idx + 0];
        idx += 11;
    }
    const float* fusion_w = (const float*)d_in[idx];
    const float* fusion_b = (const float*)d_in[idx + 1];
    int Etot = V[0].E + V[1].E + V[2].E;

    // ---- workspace carve ----
    char* w = (char*)d_ws;
    auto alloc = [&](size_t bytes) -> char* {
        char* p = w; w += (bytes + 255) & ~(size_t)255; return p;
    };
    _Float16* nf16 = (_Float16*)alloc((size_t)M * 128 * 2);
    _Float16* wts  = (_Float16*)alloc((size_t)(6 * 81920 + 49152) * 2);
    int* deg3      = (int*)alloc((size_t)3 * M * 4);
    int* cur3      = (int*)alloc((size_t)3 * M * 4);
    int* bsum      = (int*)alloc(512);
    int* off3      = (int*)alloc(((size_t)3 * M + 1) * 4);
    int* packed3   = (int*)alloc((size_t)Etot * 4);
    _Float16* T3   = (_Float16*)alloc((size_t)3 * M * 512 * 2);
    _Float16* h1b  = (_Float16*)alloc((size_t)3 * M * 128 * 2);
    _Float16* h2b  = (_Float16*)alloc((size_t)3 * M * 128 * 2);

    // WT[v][l]: [128][640]; fusTcat: [128][384]
    _Float16 *WT[3][2];
    for (int v = 0; v < 3; ++v)
        for (int l = 0; l < 2; ++l)
            WT[v][l] = wts + (size_t)(v * 2 + l) * 81920;
    _Float16* fusTcat = wts + 6 * 81920;

    // ---- prep descriptors ----
    PrepArgs pa;
    int t = 0;
    for (int v = 0; v < 3; ++v) {
        const float* bases[2] = { V[v].bases1, V[v].bases2 };
        const float* loopw[2] = { V[v].loopw1, V[v].loopw2 };
        for (int l = 0; l < 2; ++l) {
            for (int b = 0; b < 4; ++b) {
                pa.d[t].src = bases[l] + (size_t)b * 16384;
                pa.d[t].dst = WT[v][l] + (size_t)b * 128;
                pa.d[t].dstride = 640; ++t;
            }
            pa.d[t].src = loopw[l];
            pa.d[t].dst = WT[v][l] + 512;
            pa.d[t].dstride = 640; ++t;
        }
    }
    for (int v = 0; v < 3; ++v) {
        pa.d[t].src = fusion_w + (size_t)v * 16384;
        pa.d[t].dst = fusTcat + (size_t)v * 128;
        pa.d[t].dstride = 384; ++t;
    }
    prep_weights<<<33, 256, 0, stream>>>(pa);

    int n4 = M * D / 4;
    f32_to_f16<<<(n4 + 255) / 256, 256, 0, stream>>>((const float*)d_in[0], nf16, n4);

    // ---- batched CSR build ----
    EdgeArgs ea;
    for (int v = 0; v < 3; ++v) {
        ea.src[v] = V[v].src; ea.dst[v] = V[v].dst; ea.rel[v] = V[v].rel; ea.E[v] = V[v].E;
    }
    ea.N = M;
    int n3 = 3 * M;
    zero_deg<<<(n3 + 255) / 256, 256, 0, stream>>>(deg3, n3);
    hist3<<<dim3(512, 3), 256, 0, stream>>>(ea, deg3);
    int nsb = (n3 + 2047) / 2048;
    scan1_kernel<<<nsb, 256, 0, stream>>>(deg3, off3, bsum, n3);
    scan2_kernel<<<nsb, 256, 0, stream>>>(off3, cur3, bsum, n3, Etot);
    scatter3<<<dim3(512, 3), 256, 0, stream>>>(ea, cur3, packed3);

    int ng  = (M + 3) / 4;
    int gxB = (M + 127) / 128;
    size_t Tvs = (size_t)M * 512;
    size_t hvs = (size_t)M * 128;
    float* outF = (float*)d_out;

    // ---- layer 1 ----
    GatherArgs g1;
    g1.off3 = off3; g1.packed3 = packed3; g1.T = T3; g1.N = M; g1.Tvs = Tvs;
    for (int v = 0; v < 3; ++v) { g1.coef[v] = V[v].coef1; g1.h[v] = nf16; }
    gather3<<<dim3(ng, 3), 256, 0, stream>>>(g1);

    GemmArgs m1;
    m1.T = T3; m1.hout = h1b; m1.M = M; m1.relu = 1; m1.Tvs = Tvs; m1.hovs = hvs;
    for (int v = 0; v < 3; ++v) { m1.hin[v] = nf16; m1.WT[v] = WT[v][0]; m1.bias[v] = V[v].bias1; }
    gemm_layer<<<dim3(gxB, 3), 512, 0, stream>>>(m1);

    // ---- layer 2 ----
    GatherArgs g2 = g1;
    for (int v = 0; v < 3; ++v) { g2.coef[v] = V[v].coef2; g2.h[v] = h1b + (size_t)v * hvs; }
    gather3<<<dim3(ng, 3), 256, 0, stream>>>(g2);

    GemmArgs m2;
    m2.T = T3; m2.hout = h2b; m2.M = M; m2.relu = 0; m2.Tvs = Tvs; m2.hovs = hvs;
    for (int v = 0; v < 3; ++v) { m2.hin[v] = h1b + (size_t)v * hvs; m2.WT[v] = WT[v][1]; m2.bias[v] = V[v].bias2; }
    gemm_layer<<<dim3(gxB, 3), 512, 0, stream>>>(m2);

    // ---- fusion ----
    FusArgs fa;
    for (int v = 0; v < 3; ++v) fa.A[v] = h2b + (size_t)v * hvs;
    fa.BT = fusTcat; fa.bias = fusion_b; fa.out = outF; fa.M = M;
    gemm_fusion<<<gxB, 256, 0, stream>>>(fa);
}

// Round 11
// 335.515 us; speedup vs baseline: 1.3864x; 1.3864x over previous
//
#include <hip/hip_runtime.h>
#include <hip/hip_bf16.h>
#include <stdint.h>

typedef _Float16 f16x8 __attribute__((ext_vector_type(8)));
typedef _Float16 f16x2 __attribute__((ext_vector_type(2)));
typedef float f32x4 __attribute__((ext_vector_type(4)));

#define AL 136   // LDS leading dim for 128-wide fp16 tiles (+8 pad)

// ------------- weight prep: f32 [i][o] 128x128 tile -> fp16 dst[o*stride + i] -------------
struct PrepDesc { const float* src; _Float16* dst; int dstride; };
struct PrepArgs { PrepDesc d[33]; };

__global__ __launch_bounds__(256) void prep_weights(PrepArgs args) {
    __shared__ _Float16 lds[128 * 129];
    const PrepDesc de = args.d[blockIdx.x];
    int t = threadIdx.x;
    for (int q = 0; q < 64; ++q) {
        int li = t + q * 256;            // linear over src [i][o]
        int i = li >> 7, o = li & 127;
        lds[o * 129 + i] = (_Float16)de.src[li];
    }
    __syncthreads();
    for (int q = 0; q < 64; ++q) {
        int lo = t + q * 256;            // linear over dst [o][i]
        int o = lo >> 7, i = lo & 127;
        de.dst[(size_t)o * de.dstride + i] = lds[o * 129 + i];
    }
}

// ---------------- f32 -> fp16 convert ----------------
__global__ __launch_bounds__(256) void f32_to_f16(const float* __restrict__ in,
                                                  _Float16* __restrict__ out, int n4) {
    int i = blockIdx.x * 256 + threadIdx.x;
    if (i >= n4) return;
    float4 v = *((const float4*)in + i);
    f16x2 a, b;
    a[0] = (_Float16)v.x; a[1] = (_Float16)v.y;
    b[0] = (_Float16)v.z; b[1] = (_Float16)v.w;
    f16x2* o = (f16x2*)out + i * 2;
    o[0] = a; o[1] = b;
}

// ---------------- CSR build (3 views concatenated: index space [3][N]) ----------------
struct EdgeArgs {
    const int* src[3]; const int* dst[3]; const int* rel[3];
    int E[3]; int N;
};

__global__ __launch_bounds__(256) void zero_deg(int* __restrict__ deg3, int n) {
    int i = blockIdx.x * 256 + threadIdx.x;
    if (i < n) deg3[i] = 0;
}

__global__ __launch_bounds__(256) void hist3(EdgeArgs ea, int* __restrict__ deg3) {
    int v = blockIdx.y;
    const int* dst = ea.dst[v];
    int* deg = deg3 + (size_t)v * ea.N;
    for (int e = blockIdx.x * 256 + threadIdx.x; e < ea.E[v]; e += gridDim.x * 256)
        atomicAdd(&deg[dst[e]], 1);
}

__global__ __launch_bounds__(256) void scan1_kernel(const int* __restrict__ deg,
                                                    int* __restrict__ off,
                                                    int* __restrict__ bsum, int n) {
    __shared__ int s[256];
    int b = blockIdx.x, t = threadIdx.x;
    int base = b * 2048 + t * 8;
    int v[8]; int sum = 0;
    for (int j = 0; j < 8; ++j) {
        int x = (base + j < n) ? deg[base + j] : 0;
        v[j] = sum;
        sum += x;
    }
    s[t] = sum;
    __syncthreads();
    for (int st = 1; st < 256; st <<= 1) {
        int y = (t >= st) ? s[t - st] : 0;
        __syncthreads();
        s[t] += y;
        __syncthreads();
    }
    int texcl = t ? s[t - 1] : 0;
    if (t == 255) bsum[b] = s[255];
    for (int j = 0; j < 8; ++j)
        if (base + j < n) off[base + j] = texcl + v[j];
}

__global__ __launch_bounds__(256) void scan2_kernel(int* __restrict__ off,
                                                    int* __restrict__ cur,
                                                    const int* __restrict__ bsum,
                                                    int n, int Etot) {
    __shared__ int pref;
    int b = blockIdx.x, t = threadIdx.x;
    if (t == 0) { int p = 0; for (int j = 0; j < b; ++j) p += bsum[j]; pref = p; }
    __syncthreads();
    int p = pref;
    int base = b * 2048 + t * 8;
    for (int j = 0; j < 8; ++j)
        if (base + j < n) { int x = off[base + j] + p; off[base + j] = x; cur[base + j] = x; }
    if (b == 0 && t == 0) off[n] = Etot;
}

__global__ __launch_bounds__(256) void scatter3(EdgeArgs ea, int* __restrict__ cur3,
                                                int* __restrict__ packed3) {
    int v = blockIdx.y;
    const int* src = ea.src[v];
    const int* dst = ea.dst[v];
    const int* rel = ea.rel[v];
    int* cur = cur3 + (size_t)v * ea.N;
    for (int e = blockIdx.x * 256 + threadIdx.x; e < ea.E[v]; e += gridDim.x * 256) {
        int pos = atomicAdd(&cur[dst[e]], 1);
        packed3[pos] = src[e] | (rel[e] << 20);
    }
}

// ---- gather: T[v][d][b][:] = sum_{e->d} coef_v[rel_e][b] * h_v[src_e][:], one wave/node ----
struct GatherArgs {
    const int* off3;
    const int* packed3;
    const float* coef[3];     // [R][4]
    const _Float16* h[3];     // [N][128] per-view input
    _Float16* T;              // output base
    int N; size_t Tvs;
};

__global__ __launch_bounds__(256) void gather3(GatherArgs g) {
    int v = blockIdx.y;
    int node = (blockIdx.x << 2) | (threadIdx.x >> 6);
    if (node >= g.N) return;
    int lane = threadIdx.x & 63;
    const int* off = g.off3 + (size_t)v * g.N;
    const float* coef = g.coef[v];
    const _Float16* h = g.h[v];
    _Float16* T = g.T + (size_t)v * g.Tvs;

    int i  = __builtin_amdgcn_readfirstlane(off[node]);
    int e1 = __builtin_amdgcn_readfirstlane(off[node + 1]);
    float acc[8] = {};   // [b][2]

    for (; i + 3 < e1; i += 4) {
        int p0 = __builtin_amdgcn_readfirstlane(g.packed3[i]);
        int p1 = __builtin_amdgcn_readfirstlane(g.packed3[i + 1]);
        int p2 = __builtin_amdgcn_readfirstlane(g.packed3[i + 2]);
        int p3 = __builtin_amdgcn_readfirstlane(g.packed3[i + 3]);
        int s0 = p0 & 0xFFFFF, r0 = p0 >> 20;
        int s1 = p1 & 0xFFFFF, r1 = p1 >> 20;
        int s2 = p2 & 0xFFFFF, r2 = p2 >> 20;
        int s3 = p3 & 0xFFFFF, r3 = p3 >> 20;
        uint32_t q0 = ((const uint32_t*)(h + (size_t)s0 * 128))[lane];
        uint32_t q1 = ((const uint32_t*)(h + (size_t)s1 * 128))[lane];
        uint32_t q2 = ((const uint32_t*)(h + (size_t)s2 * 128))[lane];
        uint32_t q3 = ((const uint32_t*)(h + (size_t)s3 * 128))[lane];
        float4 c0 = *(const float4*)(coef + (size_t)r0 * 4);
        float4 c1 = *(const float4*)(coef + (size_t)r1 * 4);
        float4 c2 = *(const float4*)(coef + (size_t)r2 * 4);
        float4 c3 = *(const float4*)(coef + (size_t)r3 * 4);
        f16x2 u0 = __builtin_bit_cast(f16x2, q0);
        f16x2 u1 = __builtin_bit_cast(f16x2, q1);
        f16x2 u2 = __builtin_bit_cast(f16x2, q2);
        f16x2 u3 = __builtin_bit_cast(f16x2, q3);
        float lo0 = (float)u0[0], hi0 = (float)u0[1];
        float lo1 = (float)u1[0], hi1 = (float)u1[1];
        float lo2 = (float)u2[0], hi2 = (float)u2[1];
        float lo3 = (float)u3[0], hi3 = (float)u3[1];
        acc[0] += c0.x * lo0 + c1.x * lo1 + c2.x * lo2 + c3.x * lo3;
        acc[1] += c0.x * hi0 + c1.x * hi1 + c2.x * hi2 + c3.x * hi3;
        acc[2] += c0.y * lo0 + c1.y * lo1 + c2.y * lo2 + c3.y * lo3;
        acc[3] += c0.y * hi0 + c1.y * hi1 + c2.y * hi2 + c3.y * hi3;
        acc[4] += c0.z * lo0 + c1.z * lo1 + c2.z * lo2 + c3.z * lo3;
        acc[5] += c0.z * hi0 + c1.z * hi1 + c2.z * hi2 + c3.z * hi3;
        acc[6] += c0.w * lo0 + c1.w * lo1 + c2.w * lo2 + c3.w * lo3;
        acc[7] += c0.w * hi0 + c1.w * hi1 + c2.w * hi2 + c3.w * hi3;
    }
    for (; i < e1; ++i) {
        int p0 = __builtin_amdgcn_readfirstlane(g.packed3[i]);
        int s0 = p0 & 0xFFFFF, r0 = p0 >> 20;
        uint32_t q0 = ((const uint32_t*)(h + (size_t)s0 * 128))[lane];
        float4 c0 = *(const float4*)(coef + (size_t)r0 * 4);
        f16x2 u0 = __builtin_bit_cast(f16x2, q0);
        float lo0 = (float)u0[0], hi0 = (float)u0[1];
        acc[0] += c0.x * lo0;  acc[1] += c0.x * hi0;
        acc[2] += c0.y * lo0;  acc[3] += c0.y * hi0;
        acc[4] += c0.z * lo0;  acc[5] += c0.z * hi0;
        acc[6] += c0.w * lo0;  acc[7] += c0.w * hi0;
    }
    _Float16* tb = T + (size_t)node * 512 + 2 * lane;
    for (int b = 0; b < 4; ++b) {
        f16x2 o; o[0] = (_Float16)acc[2 * b]; o[1] = (_Float16)acc[2 * b + 1];
        *(f16x2*)(tb + b * 128) = o;
    }
}

// ---- layer GEMM: out = [T | h] @ BT^T + bias (+relu), K=640, BM=64 ----
// 512 thr / 8 waves (2M x 4N), per-wave 32x32; LDS 52.2 KB -> 3 blocks/CU (24 waves).
struct GemmArgs {
    const _Float16* T;        // base; +v*Tvs
    const _Float16* hin[3];
    const _Float16* WT[3];    // [128][640]
    const float* bias[3];
    _Float16* hout;           // base; +v*hovs
    int M; int relu; size_t Tvs; size_t hovs;
};

__global__ __launch_bounds__(512) void gemm_layer(GemmArgs ga) {
    __shared__ _Float16 As[64 * AL];
    __shared__ _Float16 Bs[128 * AL];
    int v = blockIdx.y;
    const _Float16* Tb  = ga.T + (size_t)v * ga.Tvs;
    const _Float16* hin = ga.hin[v];
    const _Float16* BT  = ga.WT[v];
    const float* bias   = ga.bias[v];
    _Float16* out       = ga.hout + (size_t)v * ga.hovs;
    int M = ga.M;

    int tid = threadIdx.x;
    int m0 = blockIdx.x * 64;
    int wid = tid >> 6, lane = tid & 63;
    int wr = (wid >> 2) * 32;     // 2 row groups of 32
    int wc = (wid & 3) * 32;      // 4 col groups of 32
    int lm = lane & 15;
    int lk = (lane >> 4) * 8;

    f32x4 acc[2][2] = {};

    for (int kb = 0; kb < 5; ++kb) {
        const _Float16* Asrc; size_t astride;
        if (kb < 4) { Asrc = Tb + (size_t)kb * 128; astride = 512; }
        else        { Asrc = hin;                   astride = 128; }
        for (int q = 0; q < 2; ++q) {
            int li = tid + q * 512;            // 0..1023
            int r = li >> 4;
            int c = (li & 15) << 3;
            int gr = m0 + r; if (gr >= M) gr = M - 1;
            *(f16x8*)(As + r * AL + c) = *(const f16x8*)(Asrc + (size_t)gr * astride + c);
        }
        for (int q = 0; q < 4; ++q) {
            int li = tid + q * 512;            // 0..2047
            int r = li >> 4;
            int c = (li & 15) << 3;
            *(f16x8*)(Bs + r * AL + c) = *(const f16x8*)(BT + (size_t)r * 640 + kb * 128 + c);
        }
        __syncthreads();

        for (int ks = 0; ks < 4; ++ks) {
            f16x8 a[2], b[2];
            for (int mi = 0; mi < 2; ++mi)
                a[mi] = *(const f16x8*)(As + (wr + mi * 16 + lm) * AL + ks * 32 + lk);
            for (int ni = 0; ni < 2; ++ni)
                b[ni] = *(const f16x8*)(Bs + (wc + ni * 16 + lm) * AL + ks * 32 + lk);
            for (int mi = 0; mi < 2; ++mi)
                for (int ni = 0; ni < 2; ++ni)
                    acc[mi][ni] = __builtin_amdgcn_mfma_f32_16x16x32_f16(a[mi], b[ni], acc[mi][ni], 0, 0, 0);
        }
        __syncthreads();
    }

    int rbase = (lane >> 4) * 4;
    for (int mi = 0; mi < 2; ++mi) {
        for (int j = 0; j < 4; ++j) {
            int gr = m0 + wr + mi * 16 + rbase + j;
            if (gr >= M) continue;
            for (int ni = 0; ni < 2; ++ni) {
                int col = wc + ni * 16 + lm;
                float val = acc[mi][ni][j] + bias[col];
                if (ga.relu) val = fmaxf(val, 0.f);
                out[(size_t)gr * 128 + col] = (_Float16)val;
            }
        }
    }
}

// ---- fusion GEMM: out_f32 = sum_kb A[kb] @ BT_chunk + bias, BM=128 ----
struct FusArgs {
    const _Float16* A[3];     // K-chunks, each [M][128]
    const _Float16* BT;       // [128][384]
    const float* bias;
    float* out; int M;
};

__global__ __launch_bounds__(256) void gemm_fusion(FusArgs fa) {
    __shared__ _Float16 As[128 * AL];
    __shared__ _Float16 Bs[128 * AL];
    int tid = threadIdx.x;
    int m0 = blockIdx.x * 128;
    int M = fa.M;
    int wid = tid >> 6, lane = tid & 63;
    int wr = (wid >> 1) * 64;
    int wc = (wid & 1) * 64;
    int lm = lane & 15;
    int lk = (lane >> 4) * 8;

    f32x4 acc[4][4] = {};

    for (int kb = 0; kb < 3; ++kb) {
        const _Float16* Asrc = fa.A[kb];
        for (int q = 0; q < 8; ++q) {
            int li = tid + q * 256;
            int r = li >> 4;
            int c = (li & 15) << 3;
            int gr = m0 + r; if (gr >= M) gr = M - 1;
            *(f16x8*)(As + r * AL + c) = *(const f16x8*)(Asrc + (size_t)gr * 128 + c);
        }
        for (int q = 0; q < 8; ++q) {
            int li = tid + q * 256;
            int r = li >> 4;
            int c = (li & 15) << 3;
            *(f16x8*)(Bs + r * AL + c) = *(const f16x8*)(fa.BT + (size_t)r * 384 + kb * 128 + c);
        }
        __syncthreads();

        for (int ks = 0; ks < 4; ++ks) {
            f16x8 a[4], b[4];
            for (int mi = 0; mi < 4; ++mi)
                a[mi] = *(const f16x8*)(As + (wr + mi * 16 + lm) * AL + ks * 32 + lk);
            for (int ni = 0; ni < 4; ++ni)
                b[ni] = *(const f16x8*)(Bs + (wc + ni * 16 + lm) * AL + ks * 32 + lk);
            for (int mi = 0; mi < 4; ++mi)
                for (int ni = 0; ni < 4; ++ni)
                    acc[mi][ni] = __builtin_amdgcn_mfma_f32_16x16x32_f16(a[mi], b[ni], acc[mi][ni], 0, 0, 0);
        }
        __syncthreads();
    }

    int rbase = (lane >> 4) * 4;
    for (int mi = 0; mi < 4; ++mi) {
        for (int j = 0; j < 4; ++j) {
            int gr = m0 + wr + mi * 16 + rbase + j;
            if (gr >= M) continue;
            for (int ni = 0; ni < 4; ++ni) {
                int col = wc + ni * 16 + lm;
                fa.out[(size_t)gr * 128 + col] = acc[mi][ni][j] + fa.bias[col];
            }
        }
    }
}

// ---------------- host launch ----------------
extern "C" void kernel_launch(void* const* d_in, const int* in_sizes, int n_in,
                              void* d_out, int out_size, void* d_ws, size_t ws_size,
                              hipStream_t stream) {
    const int D = 128;
    const int M = in_sizes[0] / D;

    struct ViewIn {
        const int *src, *dst, *rel;
        const float *bases1, *coef1, *loopw1, *bias1;
        const float *bases2, *coef2, *loopw2, *bias2;
        int E;
    } V[3];
    int idx = 1;
    for (int v = 0; v < 3; ++v) {
        V[v].src    = (const int*)d_in[idx + 0];
        V[v].dst    = (const int*)d_in[idx + 1];
        V[v].rel    = (const int*)d_in[idx + 2];
        V[v].bases1 = (const float*)d_in[idx + 3];
        V[v].coef1  = (const float*)d_in[idx + 4];
        V[v].loopw1 = (const float*)d_in[idx + 5];
        V[v].bias1  = (const float*)d_in[idx + 6];
        V[v].bases2 = (const float*)d_in[idx + 7];
        V[v].coef2  = (const float*)d_in[idx + 8];
        V[v].loopw2 = (const float*)d_in[idx + 9];
        V[v].bias2  = (const float*)d_in[idx + 10];
        V[v].E      = in_sizes[idx + 0];
        idx += 11;
    }
    const float* fusion_w = (const float*)d_in[idx];
    const float* fusion_b = (const float*)d_in[idx + 1];
    int Etot = V[0].E + V[1].E + V[2].E;

    // ---- workspace carve ----
    char* w = (char*)d_ws;
    auto alloc = [&](size_t bytes) -> char* {
        char* p = w; w += (bytes + 255) & ~(size_t)255; return p;
    };
    _Float16* nf16 = (_Float16*)alloc((size_t)M * 128 * 2);
    _Float16* wts  = (_Float16*)alloc((size_t)(6 * 81920 + 49152) * 2);
    int* deg3      = (int*)alloc((size_t)3 * M * 4);
    int* cur3      = (int*)alloc((size_t)3 * M * 4);
    int* bsum      = (int*)alloc(512);
    int* off3      = (int*)alloc(((size_t)3 * M + 1) * 4);
    int* packed3   = (int*)alloc((size_t)Etot * 4);
    _Float16* T3   = (_Float16*)alloc((size_t)3 * M * 512 * 2);
    _Float16* h1b  = (_Float16*)alloc((size_t)3 * M * 128 * 2);
    _Float16* h2b  = (_Float16*)alloc((size_t)3 * M * 128 * 2);

    // WT[v][l]: [128][640]; fusTcat: [128][384]
    _Float16 *WT[3][2];
    for (int v = 0; v < 3; ++v)
        for (int l = 0; l < 2; ++l)
            WT[v][l] = wts + (size_t)(v * 2 + l) * 81920;
    _Float16* fusTcat = wts + 6 * 81920;

    // ---- prep descriptors ----
    PrepArgs pa;
    int t = 0;
    for (int v = 0; v < 3; ++v) {
        const float* bases[2] = { V[v].bases1, V[v].bases2 };
        const float* loopw[2] = { V[v].loopw1, V[v].loopw2 };
        for (int l = 0; l < 2; ++l) {
            for (int b = 0; b < 4; ++b) {
                pa.d[t].src = bases[l] + (size_t)b * 16384;
                pa.d[t].dst = WT[v][l] + (size_t)b * 128;
                pa.d[t].dstride = 640; ++t;
            }
            pa.d[t].src = loopw[l];
            pa.d[t].dst = WT[v][l] + 512;
            pa.d[t].dstride = 640; ++t;
        }
    }
    for (int v = 0; v < 3; ++v) {
        pa.d[t].src = fusion_w + (size_t)v * 16384;
        pa.d[t].dst = fusTcat + (size_t)v * 128;
        pa.d[t].dstride = 384; ++t;
    }
    prep_weights<<<33, 256, 0, stream>>>(pa);

    int n4 = M * D / 4;
    f32_to_f16<<<(n4 + 255) / 256, 256, 0, stream>>>((const float*)d_in[0], nf16, n4);

    // ---- batched CSR build ----
    EdgeArgs ea;
    for (int v = 0; v < 3; ++v) {
        ea.src[v] = V[v].src; ea.dst[v] = V[v].dst; ea.rel[v] = V[v].rel; ea.E[v] = V[v].E;
    }
    ea.N = M;
    int n3 = 3 * M;
    zero_deg<<<(n3 + 255) / 256, 256, 0, stream>>>(deg3, n3);
    hist3<<<dim3(512, 3), 256, 0, stream>>>(ea, deg3);
    int nsb = (n3 + 2047) / 2048;
    scan1_kernel<<<nsb, 256, 0, stream>>>(deg3, off3, bsum, n3);
    scan2_kernel<<<nsb, 256, 0, stream>>>(off3, cur3, bsum, n3, Etot);
    scatter3<<<dim3(512, 3), 256, 0, stream>>>(ea, cur3, packed3);

    int ng  = (M + 3) / 4;
    int gxL = (M + 63) / 64;
    int gxF = (M + 127) / 128;
    size_t Tvs = (size_t)M * 512;
    size_t hvs = (size_t)M * 128;
    float* outF = (float*)d_out;

    // ---- layer 1 ----
    GatherArgs g1;
    g1.off3 = off3; g1.packed3 = packed3; g1.T = T3; g1.N = M; g1.Tvs = Tvs;
    for (int v = 0; v < 3; ++v) { g1.coef[v] = V[v].coef1; g1.h[v] = nf16; }
    gather3<<<dim3(ng, 3), 256, 0, stream>>>(g1);

    GemmArgs m1;
    m1.T = T3; m1.hout = h1b; m1.M = M; m1.relu = 1; m1.Tvs = Tvs; m1.hovs = hvs;
    for (int v = 0; v < 3; ++v) { m1.hin[v] = nf16; m1.WT[v] = WT[v][0]; m1.bias[v] = V[v].bias1; }
    gemm_layer<<<dim3(gxL, 3), 512, 0, stream>>>(m1);

    // ---- layer 2 ----
    GatherArgs g2 = g1;
    for (int v = 0; v < 3; ++v) { g2.coef[v] = V[v].coef2; g2.h[v] = h1b + (size_t)v * hvs; }
    gather3<<<dim3(ng, 3), 256, 0, stream>>>(g2);

    GemmArgs m2;
    m2.T = T3; m2.hout = h2b; m2.M = M; m2.relu = 0; m2.Tvs = Tvs; m2.hovs = hvs;
    for (int v = 0; v < 3; ++v) { m2.hin[v] = h1b + (size_t)v * hvs; m2.WT[v] = WT[v][1]; m2.bias[v] = V[v].bias2; }
    gemm_layer<<<dim3(gxL, 3), 512, 0, stream>>>(m2);

    // ---- fusion ----
    FusArgs fa;
    for (int v = 0; v < 3; ++v) fa.A[v] = h2b + (size_t)v * hvs;
    fa.BT = fusTcat; fa.bias = fusion_b; fa.out = outF; fa.M = M;
    gemm_fusion<<<gxF, 256, 0, stream>>>(fa);
}

// Round 12
// 331.718 us; speedup vs baseline: 1.4022x; 1.0114x over previous
//
#include <hip/hip_runtime.h>
#include <hip/hip_bf16.h>
#include <stdint.h>

typedef _Float16 f16x8 __attribute__((ext_vector_type(8)));
typedef _Float16 f16x2 __attribute__((ext_vector_type(2)));
typedef float f32x4 __attribute__((ext_vector_type(4)));

// All fp16 activation/weight buffers are stored ROW-SWIZZLED: within each
// 128-col chunk, element col c of row r lives at c ^ ((r&7)<<3). This makes
// linear global_load_lds staging + conflict-free ds_read_b128 possible.

__device__ __forceinline__ void gll16(const _Float16* g, _Float16* l) {
    __builtin_amdgcn_global_load_lds(
        (const __attribute__((address_space(1))) void*)g,
        (__attribute__((address_space(3))) void*)l, 16, 0, 0);
}

// ------------- weight prep: f32 [i][o] 128x128 tile -> fp16 dst[o][i^swz(o)] -------------
struct PrepDesc { const float* src; _Float16* dst; int dstride; };
struct PrepArgs { PrepDesc d[33]; };

__global__ __launch_bounds__(256) void prep_weights(PrepArgs args) {
    __shared__ _Float16 lds[128 * 129];
    const PrepDesc de = args.d[blockIdx.x];
    int t = threadIdx.x;
    for (int q = 0; q < 64; ++q) {
        int li = t + q * 256;            // linear over src [i][o]
        int i = li >> 7, o = li & 127;
        lds[o * 129 + i] = (_Float16)de.src[li];
    }
    __syncthreads();
    for (int q = 0; q < 64; ++q) {
        int lo = t + q * 256;            // linear over dst [o][i]
        int o = lo >> 7, i = lo & 127;
        de.dst[(size_t)o * de.dstride + (i ^ ((o & 7) << 3))] = lds[o * 129 + i];
    }
}

// ---------------- f32 -> fp16 convert (row-swizzled output) ----------------
__global__ __launch_bounds__(256) void f32_to_f16(const float* __restrict__ in,
                                                  _Float16* __restrict__ out, int n4) {
    int i = blockIdx.x * 256 + threadIdx.x;
    if (i >= n4) return;
    float4 v = *((const float4*)in + i);
    int n = i >> 5;
    int c = (i & 31) * 4;
    int cs = c ^ ((n & 7) << 3);
    f16x2 a, b;
    a[0] = (_Float16)v.x; a[1] = (_Float16)v.y;
    b[0] = (_Float16)v.z; b[1] = (_Float16)v.w;
    _Float16* o = out + (size_t)n * 128 + cs;
    *(f16x2*)o = a;
    *(f16x2*)(o + 2) = b;
}

// ---------------- CSR build (3 views concatenated) ----------------
struct EdgeArgs {
    const int* src[3]; const int* dst[3]; const int* rel[3];
    int E[3]; int N;
};

__global__ __launch_bounds__(256) void zero_deg(int* __restrict__ deg3, int n) {
    int i = blockIdx.x * 256 + threadIdx.x;
    if (i < n) deg3[i] = 0;
}

__global__ __launch_bounds__(256) void hist3(EdgeArgs ea, int* __restrict__ deg3) {
    int v = blockIdx.y;
    const int* dst = ea.dst[v];
    int* deg = deg3 + (size_t)v * ea.N;
    for (int e = blockIdx.x * 256 + threadIdx.x; e < ea.E[v]; e += gridDim.x * 256)
        atomicAdd(&deg[dst[e]], 1);
}

__global__ __launch_bounds__(256) void scan1_kernel(const int* __restrict__ deg,
                                                    int* __restrict__ off,
                                                    int* __restrict__ bsum, int n) {
    __shared__ int s[256];
    int b = blockIdx.x, t = threadIdx.x;
    int base = b * 2048 + t * 8;
    int v[8]; int sum = 0;
    for (int j = 0; j < 8; ++j) {
        int x = (base + j < n) ? deg[base + j] : 0;
        v[j] = sum;
        sum += x;
    }
    s[t] = sum;
    __syncthreads();
    for (int st = 1; st < 256; st <<= 1) {
        int y = (t >= st) ? s[t - st] : 0;
        __syncthreads();
        s[t] += y;
        __syncthreads();
    }
    int texcl = t ? s[t - 1] : 0;
    if (t == 255) bsum[b] = s[255];
    for (int j = 0; j < 8; ++j)
        if (base + j < n) off[base + j] = texcl + v[j];
}

__global__ __launch_bounds__(256) void scan2_kernel(int* __restrict__ off,
                                                    int* __restrict__ cur,
                                                    const int* __restrict__ bsum,
                                                    int n, int Etot) {
    __shared__ int pref;
    int b = blockIdx.x, t = threadIdx.x;
    if (t == 0) { int p = 0; for (int j = 0; j < b; ++j) p += bsum[j]; pref = p; }
    __syncthreads();
    int p = pref;
    int base = b * 2048 + t * 8;
    for (int j = 0; j < 8; ++j)
        if (base + j < n) { int x = off[base + j] + p; off[base + j] = x; cur[base + j] = x; }
    if (b == 0 && t == 0) off[n] = Etot;
}

__global__ __launch_bounds__(256) void scatter3(EdgeArgs ea, int* __restrict__ cur3,
                                                int* __restrict__ packed3) {
    int v = blockIdx.y;
    const int* src = ea.src[v];
    const int* dst = ea.dst[v];
    const int* rel = ea.rel[v];
    int* cur = cur3 + (size_t)v * ea.N;
    for (int e = blockIdx.x * 256 + threadIdx.x; e < ea.E[v]; e += gridDim.x * 256) {
        int pos = atomicAdd(&cur[dst[e]], 1);
        packed3[pos] = src[e] | (rel[e] << 20);
    }
}

// ---- gather: T[v][d][b][:] += coef*h[src]; h is row-swizzled, T written row-swizzled ----
struct GatherArgs {
    const int* off3;
    const int* packed3;
    const float* coef[3];     // [R][4]
    const _Float16* h[3];     // [N][128] swizzled
    _Float16* T;              // [N][4][128] swizzled per node
    int N; size_t Tvs;
};

__global__ __launch_bounds__(256) void gather3(GatherArgs g) {
    int v = blockIdx.y;
    int node = (blockIdx.x << 2) | (threadIdx.x >> 6);
    if (node >= g.N) return;
    int lane = threadIdx.x & 63;
    const int* off = g.off3 + (size_t)v * g.N;
    const float* coef = g.coef[v];
    const _Float16* h = g.h[v];
    _Float16* T = g.T + (size_t)v * g.Tvs;

    int i  = __builtin_amdgcn_readfirstlane(off[node]);
    int e1 = __builtin_amdgcn_readfirstlane(off[node + 1]);
    float acc[8] = {};   // [b][2]

    for (; i + 3 < e1; i += 4) {
        int p0 = __builtin_amdgcn_readfirstlane(g.packed3[i]);
        int p1 = __builtin_amdgcn_readfirstlane(g.packed3[i + 1]);
        int p2 = __builtin_amdgcn_readfirstlane(g.packed3[i + 2]);
        int p3 = __builtin_amdgcn_readfirstlane(g.packed3[i + 3]);
        int s0 = p0 & 0xFFFFF, r0 = p0 >> 20;
        int s1 = p1 & 0xFFFFF, r1 = p1 >> 20;
        int s2 = p2 & 0xFFFFF, r2 = p2 >> 20;
        int s3 = p3 & 0xFFFFF, r3 = p3 >> 20;
        // unswizzle on read: dword index lane ^ ((row&7)<<2)
        uint32_t q0 = ((const uint32_t*)(h + (size_t)s0 * 128))[lane ^ ((s0 & 7) << 2)];
        uint32_t q1 = ((const uint32_t*)(h + (size_t)s1 * 128))[lane ^ ((s1 & 7) << 2)];
        uint32_t q2 = ((const uint32_t*)(h + (size_t)s2 * 128))[lane ^ ((s2 & 7) << 2)];
        uint32_t q3 = ((const uint32_t*)(h + (size_t)s3 * 128))[lane ^ ((s3 & 7) << 2)];
        float4 c0 = *(const float4*)(coef + (size_t)r0 * 4);
        float4 c1 = *(const float4*)(coef + (size_t)r1 * 4);
        float4 c2 = *(const float4*)(coef + (size_t)r2 * 4);
        float4 c3 = *(const float4*)(coef + (size_t)r3 * 4);
        f16x2 u0 = __builtin_bit_cast(f16x2, q0);
        f16x2 u1 = __builtin_bit_cast(f16x2, q1);
        f16x2 u2 = __builtin_bit_cast(f16x2, q2);
        f16x2 u3 = __builtin_bit_cast(f16x2, q3);
        float lo0 = (float)u0[0], hi0 = (float)u0[1];
        float lo1 = (float)u1[0], hi1 = (float)u1[1];
        float lo2 = (float)u2[0], hi2 = (float)u2[1];
        float lo3 = (float)u3[0], hi3 = (float)u3[1];
        acc[0] += c0.x * lo0 + c1.x * lo1 + c2.x * lo2 + c3.x * lo3;
        acc[1] += c0.x * hi0 + c1.x * hi1 + c2.x * hi2 + c3.x * hi3;
        acc[2] += c0.y * lo0 + c1.y * lo1 + c2.y * lo2 + c3.y * lo3;
        acc[3] += c0.y * hi0 + c1.y * hi1 + c2.y * hi2 + c3.y * hi3;
        acc[4] += c0.z * lo0 + c1.z * lo1 + c2.z * lo2 + c3.z * lo3;
        acc[5] += c0.z * hi0 + c1.z * hi1 + c2.z * hi2 + c3.z * hi3;
        acc[6] += c0.w * lo0 + c1.w * lo1 + c2.w * lo2 + c3.w * lo3;
        acc[7] += c0.w * hi0 + c1.w * hi1 + c2.w * hi2 + c3.w * hi3;
    }
    for (; i < e1; ++i) {
        int p0 = __builtin_amdgcn_readfirstlane(g.packed3[i]);
        int s0 = p0 & 0xFFFFF, r0 = p0 >> 20;
        uint32_t q0 = ((const uint32_t*)(h + (size_t)s0 * 128))[lane ^ ((s0 & 7) << 2)];
        float4 c0 = *(const float4*)(coef + (size_t)r0 * 4);
        f16x2 u0 = __builtin_bit_cast(f16x2, q0);
        float lo0 = (float)u0[0], hi0 = (float)u0[1];
        acc[0] += c0.x * lo0;  acc[1] += c0.x * hi0;
        acc[2] += c0.y * lo0;  acc[3] += c0.y * hi0;
        acc[4] += c0.z * lo0;  acc[5] += c0.z * hi0;
        acc[6] += c0.w * lo0;  acc[7] += c0.w * hi0;
    }
    int cs = (2 * lane) ^ ((node & 7) << 3);   // swizzled col within each 128-chunk
    _Float16* tb = T + (size_t)node * 512 + cs;
    for (int b = 0; b < 4; ++b) {
        f16x2 o; o[0] = (_Float16)acc[2 * b]; o[1] = (_Float16)acc[2 * b + 1];
        *(f16x2*)(tb + b * 128) = o;
    }
}

// ---- layer GEMM: out = [T | h] @ BT^T + bias (+relu), K=640, BM=64 ----
// global_load_lds staging into unpadded LDS; swizzled fragment reads. 48 KB -> 3 blk/CU.
struct GemmArgs {
    const _Float16* T;        // base; +v*Tvs (swizzled)
    const _Float16* hin[3];   // swizzled
    const _Float16* WT[3];    // [128][640] swizzled per 128-chunk
    const float* bias[3];
    _Float16* hout;           // base; +v*hovs (written swizzled)
    int M; int relu; size_t Tvs; size_t hovs;
};

__global__ __launch_bounds__(512) void gemm_layer(GemmArgs ga) {
    __shared__ _Float16 As[64 * 128];
    __shared__ _Float16 Bs[128 * 128];
    int v = blockIdx.y;
    const _Float16* Tb  = ga.T + (size_t)v * ga.Tvs;
    const _Float16* hin = ga.hin[v];
    const _Float16* BT  = ga.WT[v];
    const float* bias   = ga.bias[v];
    _Float16* out       = ga.hout + (size_t)v * ga.hovs;
    int M = ga.M;

    int tid = threadIdx.x;
    int m0 = blockIdx.x * 64;
    int wid = tid >> 6, lane = tid & 63;
    int wr = (wid >> 2) * 32;     // 2 row groups of 32
    int wc = (wid & 3) * 32;      // 4 col groups of 32
    int lm = lane & 15;
    int lk = (lane >> 4) * 8;
    int xm = (lm & 7) << 3;       // per-lane read swizzle

    f32x4 acc[2][2] = {};

    for (int kb = 0; kb < 5; ++kb) {
        const _Float16* Asrc; size_t astride;
        if (kb < 4) { Asrc = Tb + (size_t)kb * 128; astride = 512; }
        else        { Asrc = hin;                   astride = 128; }
        for (int q = 0; q < 2; ++q) {
            int li = tid + q * 512;            // 0..1023
            int r = li >> 4;
            int c = (li & 15) << 3;
            int gr = m0 + r; if (gr >= M) gr = M - 1;
            gll16(Asrc + (size_t)gr * astride + c, As + (size_t)li * 8);
        }
        for (int q = 0; q < 4; ++q) {
            int li = tid + q * 512;            // 0..2047
            gll16(BT + (size_t)(li >> 4) * 640 + kb * 128 + ((li & 15) << 3),
                  Bs + (size_t)li * 8);
        }
        __syncthreads();

        for (int ks = 0; ks < 4; ++ks) {
            int ac = (ks * 32 + lk) ^ xm;
            f16x8 a[2], b[2];
            for (int mi = 0; mi < 2; ++mi)
                a[mi] = *(const f16x8*)(As + (wr + mi * 16 + lm) * 128 + ac);
            for (int ni = 0; ni < 2; ++ni)
                b[ni] = *(const f16x8*)(Bs + (wc + ni * 16 + lm) * 128 + ac);
            for (int mi = 0; mi < 2; ++mi)
                for (int ni = 0; ni < 2; ++ni)
                    acc[mi][ni] = __builtin_amdgcn_mfma_f32_16x16x32_f16(a[mi], b[ni], acc[mi][ni], 0, 0, 0);
        }
        __syncthreads();
    }

    int rbase = (lane >> 4) * 4;
    for (int mi = 0; mi < 2; ++mi) {
        for (int j = 0; j < 4; ++j) {
            int gr = m0 + wr + mi * 16 + rbase + j;
            if (gr >= M) continue;
            int rs = (gr & 7) << 3;
            for (int ni = 0; ni < 2; ++ni) {
                int col = wc + ni * 16 + lm;
                float val = acc[mi][ni][j] + bias[col];
                if (ga.relu) val = fmaxf(val, 0.f);
                out[(size_t)gr * 128 + (col ^ rs)] = (_Float16)val;
            }
        }
    }
}

// ---- fusion GEMM: out_f32 = sum_kb A[kb] @ BT_chunk + bias, BM=128, unswizzled output ----
struct FusArgs {
    const _Float16* A[3];     // K-chunks, each [M][128] swizzled
    const _Float16* BT;       // [128][384] swizzled per 128-chunk
    const float* bias;
    float* out; int M;
};

__global__ __launch_bounds__(256) void gemm_fusion(FusArgs fa) {
    __shared__ _Float16 As[128 * 128];
    __shared__ _Float16 Bs[128 * 128];
    int tid = threadIdx.x;
    int m0 = blockIdx.x * 128;
    int M = fa.M;
    int wid = tid >> 6, lane = tid & 63;
    int wr = (wid >> 1) * 64;
    int wc = (wid & 1) * 64;
    int lm = lane & 15;
    int lk = (lane >> 4) * 8;
    int xm = (lm & 7) << 3;

    f32x4 acc[4][4] = {};

    for (int kb = 0; kb < 3; ++kb) {
        const _Float16* Asrc = fa.A[kb];
        for (int q = 0; q < 8; ++q) {
            int li = tid + q * 256;            // 0..2047
            int r = li >> 4;
            int c = (li & 15) << 3;
            int gr = m0 + r; if (gr >= M) gr = M - 1;
            gll16(Asrc + (size_t)gr * 128 + c, As + (size_t)li * 8);
        }
        for (int q = 0; q < 8; ++q) {
            int li = tid + q * 256;
            gll16(fa.BT + (size_t)(li >> 4) * 384 + kb * 128 + ((li & 15) << 3),
                  Bs + (size_t)li * 8);
        }
        __syncthreads();

        for (int ks = 0; ks < 4; ++ks) {
            int ac = (ks * 32 + lk) ^ xm;
            f16x8 a[4], b[4];
            for (int mi = 0; mi < 4; ++mi)
                a[mi] = *(const f16x8*)(As + (wr + mi * 16 + lm) * 128 + ac);
            for (int ni = 0; ni < 4; ++ni)
                b[ni] = *(const f16x8*)(Bs + (wc + ni * 16 + lm) * 128 + ac);
            for (int mi = 0; mi < 4; ++mi)
                for (int ni = 0; ni < 4; ++ni)
                    acc[mi][ni] = __builtin_amdgcn_mfma_f32_16x16x32_f16(a[mi], b[ni], acc[mi][ni], 0, 0, 0);
        }
        __syncthreads();
    }

    int rbase = (lane >> 4) * 4;
    for (int mi = 0; mi < 4; ++mi) {
        for (int j = 0; j < 4; ++j) {
            int gr = m0 + wr + mi * 16 + rbase + j;
            if (gr >= M) continue;
            for (int ni = 0; ni < 4; ++ni) {
                int col = wc + ni * 16 + lm;
                fa.out[(size_t)gr * 128 + col] = acc[mi][ni][j] + fa.bias[col];
            }
        }
    }
}

// ---------------- host launch ----------------
extern "C" void kernel_launch(void* const* d_in, const int* in_sizes, int n_in,
                              void* d_out, int out_size, void* d_ws, size_t ws_size,
                              hipStream_t stream) {
    const int D = 128;
    const int M = in_sizes[0] / D;

    struct ViewIn {
        const int *src, *dst, *rel;
        const float *bases1, *coef1, *loopw1, *bias1;
        const float *bases2, *coef2, *loopw2, *bias2;
        int E;
    } V[3];
    int idx = 1;
    for (int v = 0; v < 3; ++v) {
        V[v].src    = (const int*)d_in[idx + 0];
        V[v].dst    = (const int*)d_in[idx + 1];
        V[v].rel    = (const int*)d_in[idx + 2];
        V[v].bases1 = (const float*)d_in[idx + 3];
        V[v].coef1  = (const float*)d_in[idx + 4];
        V[v].loopw1 = (const float*)d_in[idx + 5];
        V[v].bias1  = (const float*)d_in[idx + 6];
        V[v].bases2 = (const float*)d_in[idx + 7];
        V[v].coef2  = (const float*)d_in[idx + 8];
        V[v].loopw2 = (const float*)d_in[idx + 9];
        V[v].bias2  = (const float*)d_in[idx + 10];
        V[v].E      = in_sizes[idx + 0];
        idx += 11;
    }
    const float* fusion_w = (const float*)d_in[idx];
    const float* fusion_b = (const float*)d_in[idx + 1];
    int Etot = V[0].E + V[1].E + V[2].E;

    // ---- workspace carve ----
    char* w = (char*)d_ws;
    auto alloc = [&](size_t bytes) -> char* {
        char* p = w; w += (bytes + 255) & ~(size_t)255; return p;
    };
    _Float16* nf16 = (_Float16*)alloc((size_t)M * 128 * 2);
    _Float16* wts  = (_Float16*)alloc((size_t)(6 * 81920 + 49152) * 2);
    int* deg3      = (int*)alloc((size_t)3 * M * 4);
    int* cur3      = (int*)alloc((size_t)3 * M * 4);
    int* bsum      = (int*)alloc(512);
    int* off3      = (int*)alloc(((size_t)3 * M + 1) * 4);
    int* packed3   = (int*)alloc((size_t)Etot * 4);
    _Float16* T3   = (_Float16*)alloc((size_t)3 * M * 512 * 2);
    _Float16* h1b  = (_Float16*)alloc((size_t)3 * M * 128 * 2);
    _Float16* h2b  = (_Float16*)alloc((size_t)3 * M * 128 * 2);

    // WT[v][l]: [128][640]; fusTcat: [128][384]
    _Float16 *WT[3][2];
    for (int v = 0; v < 3; ++v)
        for (int l = 0; l < 2; ++l)
            WT[v][l] = wts + (size_t)(v * 2 + l) * 81920;
    _Float16* fusTcat = wts + 6 * 81920;

    // ---- prep descriptors ----
    PrepArgs pa;
    int t = 0;
    for (int v = 0; v < 3; ++v) {
        const float* bases[2] = { V[v].bases1, V[v].bases2 };
        const float* loopw[2] = { V[v].loopw1, V[v].loopw2 };
        for (int l = 0; l < 2; ++l) {
            for (int b = 0; b < 4; ++b) {
                pa.d[t].src = bases[l] + (size_t)b * 16384;
                pa.d[t].dst = WT[v][l] + (size_t)b * 128;
                pa.d[t].dstride = 640; ++t;
            }
            pa.d[t].src = loopw[l];
            pa.d[t].dst = WT[v][l] + 512;
            pa.d[t].dstride = 640; ++t;
        }
    }
    for (int v = 0; v < 3; ++v) {
        pa.d[t].src = fusion_w + (size_t)v * 16384;
        pa.d[t].dst = fusTcat + (size_t)v * 128;
        pa.d[t].dstride = 384; ++t;
    }
    prep_weights<<<33, 256, 0, stream>>>(pa);

    int n4 = M * D / 4;
    f32_to_f16<<<(n4 + 255) / 256, 256, 0, stream>>>((const float*)d_in[0], nf16, n4);

    // ---- batched CSR build ----
    EdgeArgs ea;
    for (int v = 0; v < 3; ++v) {
        ea.src[v] = V[v].src; ea.dst[v] = V[v].dst; ea.rel[v] = V[v].rel; ea.E[v] = V[v].E;
    }
    ea.N = M;
    int n3 = 3 * M;
    zero_deg<<<(n3 + 255) / 256, 256, 0, stream>>>(deg3, n3);
    hist3<<<dim3(512, 3), 256, 0, stream>>>(ea, deg3);
    int nsb = (n3 + 2047) / 2048;
    scan1_kernel<<<nsb, 256, 0, stream>>>(deg3, off3, bsum, n3);
    scan2_kernel<<<nsb, 256, 0, stream>>>(off3, cur3, bsum, n3, Etot);
    scatter3<<<dim3(512, 3), 256, 0, stream>>>(ea, cur3, packed3);

    int ng  = (M + 3) / 4;
    int gxL = (M + 63) / 64;
    int gxF = (M + 127) / 128;
    size_t Tvs = (size_t)M * 512;
    size_t hvs = (size_t)M * 128;
    float* outF = (float*)d_out;

    // ---- layer 1 ----
    GatherArgs g1;
    g1.off3 = off3; g1.packed3 = packed3; g1.T = T3; g1.N = M; g1.Tvs = Tvs;
    for (int v = 0; v < 3; ++v) { g1.coef[v] = V[v].coef1; g1.h[v] = nf16; }
    gather3<<<dim3(ng, 3), 256, 0, stream>>>(g1);

    GemmArgs m1;
    m1.T = T3; m1.hout = h1b; m1.M = M; m1.relu = 1; m1.Tvs = Tvs; m1.hovs = hvs;
    for (int v = 0; v < 3; ++v) { m1.hin[v] = nf16; m1.WT[v] = WT[v][0]; m1.bias[v] = V[v].bias1; }
    gemm_layer<<<dim3(gxL, 3), 512, 0, stream>>>(m1);

    // ---- layer 2 ----
    GatherArgs g2 = g1;
    for (int v = 0; v < 3; ++v) { g2.coef[v] = V[v].coef2; g2.h[v] = h1b + (size_t)v * hvs; }
    gather3<<<dim3(ng, 3), 256, 0, stream>>>(g2);

    GemmArgs m2;
    m2.T = T3; m2.hout = h2b; m2.M = M; m2.relu = 0; m2.Tvs = Tvs; m2.hovs = hvs;
    for (int v = 0; v < 3; ++v) { m2.hin[v] = h1b + (size_t)v * hvs; m2.WT[v] = WT[v][1]; m2.bias[v] = V[v].bias2; }
    gemm_layer<<<dim3(gxL, 3), 512, 0, stream>>>(m2);

    // ---- fusion ----
    FusArgs fa;
    for (int v = 0; v < 3; ++v) fa.A[v] = h2b + (size_t)v * hvs;
    fa.BT = fusTcat; fa.bias = fusion_b; fa.out = outF; fa.M = M;
    gemm_fusion<<<gxF, 256, 0, stream>>>(fa);
}

// Round 13
// 288.881 us; speedup vs baseline: 1.6102x; 1.1483x over previous
//
#include <hip/hip_runtime.h>
#include <hip/hip_bf16.h>
#include <stdint.h>

typedef _Float16 f16x8 __attribute__((ext_vector_type(8)));
typedef _Float16 f16x2 __attribute__((ext_vector_type(2)));
typedef float f32x4 __attribute__((ext_vector_type(4)));

// All fp16 activation/weight buffers are stored ROW-SWIZZLED: within each
// 128-col chunk, element col c of row r lives at c ^ ((r&7)<<3).

__device__ __forceinline__ void gll16(const _Float16* g, _Float16* l) {
    __builtin_amdgcn_global_load_lds(
        (const __attribute__((address_space(1))) void*)g,
        (__attribute__((address_space(3))) void*)l, 16, 0, 0);
}

// ------------- weight prep: f32 [i][o] 128x128 tile -> fp16 dst[o][i^swz(o)] -------------
struct PrepDesc { const float* src; _Float16* dst; int dstride; };
struct PrepArgs { PrepDesc d[33]; };

__global__ __launch_bounds__(256) void prep_weights(PrepArgs args) {
    __shared__ _Float16 lds[128 * 129];
    const PrepDesc de = args.d[blockIdx.x];
    int t = threadIdx.x;
    for (int q = 0; q < 64; ++q) {
        int li = t + q * 256;            // linear over src [i][o]
        int i = li >> 7, o = li & 127;
        lds[o * 129 + i] = (_Float16)de.src[li];
    }
    __syncthreads();
    for (int q = 0; q < 64; ++q) {
        int lo = t + q * 256;            // linear over dst [o][i]
        int o = lo >> 7, i = lo & 127;
        de.dst[(size_t)o * de.dstride + (i ^ ((o & 7) << 3))] = lds[o * 129 + i];
    }
}

// ---------------- f32 -> fp16 convert (row-swizzled output) ----------------
__global__ __launch_bounds__(256) void f32_to_f16(const float* __restrict__ in,
                                                  _Float16* __restrict__ out, int n4) {
    int i = blockIdx.x * 256 + threadIdx.x;
    if (i >= n4) return;
    float4 v = *((const float4*)in + i);
    int n = i >> 5;
    int c = (i & 31) * 4;
    int cs = c ^ ((n & 7) << 3);
    f16x2 a, b;
    a[0] = (_Float16)v.x; a[1] = (_Float16)v.y;
    b[0] = (_Float16)v.z; b[1] = (_Float16)v.w;
    _Float16* o = out + (size_t)n * 128 + cs;
    *(f16x2*)o = a;
    *(f16x2*)(o + 2) = b;
}

// ---------------- CSR build via block-local counting sort (no global atomics) ----------
// Edge order: (view, bucket=dst>>8, block, seq). K1 hist -> scan -> K3 bucket scatter
// (LDS counters, bucket-contiguous mid) -> K4 per-bucket finalize (off3 + packed3).
struct EdgeArgs {
    const int* src[3]; const int* dst[3]; const int* rel[3];
    int E[3]; int N;
};

__global__ __launch_bounds__(256) void bhist(EdgeArgs ea, int* __restrict__ hmat, int nbk) {
    __shared__ int cnt[256];
    int v = blockIdx.y, blk = blockIdx.x, t = threadIdx.x;
    cnt[t] = 0;
    __syncthreads();
    int E = ea.E[v];
    const int* dst = ea.dst[v];
    int chunk = (E + 63) >> 6;
    int e0 = blk * chunk;
    int e1 = min(e0 + chunk, E);
    for (int e = e0 + t; e < e1; e += 256)
        atomicAdd(&cnt[dst[e] >> 8], 1);
    __syncthreads();
    if (t < nbk)
        hmat[((size_t)v * nbk + t) * 64 + blk] = cnt[t];
}

__global__ __launch_bounds__(256) void scan1_kernel(const int* __restrict__ deg,
                                                    int* __restrict__ off,
                                                    int* __restrict__ bsum, int n) {
    __shared__ int s[256];
    int b = blockIdx.x, t = threadIdx.x;
    int base = b * 2048 + t * 8;
    int v[8]; int sum = 0;
    for (int j = 0; j < 8; ++j) {
        int x = (base + j < n) ? deg[base + j] : 0;
        v[j] = sum;
        sum += x;
    }
    s[t] = sum;
    __syncthreads();
    for (int st = 1; st < 256; st <<= 1) {
        int y = (t >= st) ? s[t - st] : 0;
        __syncthreads();
        s[t] += y;
        __syncthreads();
    }
    int texcl = t ? s[t - 1] : 0;
    if (t == 255) bsum[b] = s[255];
    for (int j = 0; j < 8; ++j)
        if (base + j < n) off[base + j] = texcl + v[j];
}

__global__ __launch_bounds__(256) void scan2b(int* __restrict__ off,
                                              const int* __restrict__ bsum,
                                              int n, int Etot) {
    __shared__ int pref;
    int b = blockIdx.x, t = threadIdx.x;
    if (t == 0) { int p = 0; for (int j = 0; j < b; ++j) p += bsum[j]; pref = p; }
    __syncthreads();
    int p = pref;
    int base = b * 2048 + t * 8;
    for (int j = 0; j < 8; ++j)
        if (base + j < n) off[base + j] += p;
    if (b == 0 && t == 0) off[n] = Etot;
}

// mid record: src (16b) | rel (4b @16) | dst&255 (8b @20)
__global__ __launch_bounds__(256) void bscat(EdgeArgs ea, const int* __restrict__ smat,
                                             int* __restrict__ mid, int nbk) {
    __shared__ int cur[256];
    int v = blockIdx.y, blk = blockIdx.x, t = threadIdx.x;
    if (t < nbk) cur[t] = smat[((size_t)v * nbk + t) * 64 + blk];
    __syncthreads();
    int E = ea.E[v];
    const int* src = ea.src[v];
    const int* dst = ea.dst[v];
    const int* rel = ea.rel[v];
    int chunk = (E + 63) >> 6;
    int e0 = blk * chunk;
    int e1 = min(e0 + chunk, E);
    for (int e = e0 + t; e < e1; e += 256) {
        int d = dst[e];
        int pos = atomicAdd(&cur[d >> 8], 1);
        mid[pos] = src[e] | (rel[e] << 16) | ((d & 255) << 20);
    }
}

__global__ __launch_bounds__(256) void bfinal(const int* __restrict__ smat,
                                              const int* __restrict__ mid,
                                              int* __restrict__ off3,
                                              int* __restrict__ packed3,
                                              int M, int nbk, int Etot) {
    __shared__ int cnt[256];
    __shared__ int s[256];
    __shared__ int cur[256];
    int bk = blockIdx.x, v = blockIdx.y, t = threadIdx.x;
    int flat0 = (v * nbk + bk) * 64;
    int start = smat[flat0];
    int end   = smat[flat0 + 64];   // next bucket's start; smat[n]=Etot covers the last
    cnt[t] = 0;
    __syncthreads();
    for (int i = start + t; i < end; i += 256)
        atomicAdd(&cnt[(mid[i] >> 20) & 255], 1);
    __syncthreads();
    s[t] = cnt[t];
    __syncthreads();
    for (int st = 1; st < 256; st <<= 1) {
        int y = (t >= st) ? s[t - st] : 0;
        __syncthreads();
        s[t] += y;
        __syncthreads();
    }
    int excl = t ? s[t - 1] : 0;
    int node = (bk << 8) + t;
    if (node < M) off3[(size_t)v * M + node] = start + excl;
    cur[t] = start + excl;
    __syncthreads();
    for (int i = start + t; i < end; i += 256) {
        int m = mid[i];
        int pos = atomicAdd(&cur[(m >> 20) & 255], 1);
        packed3[pos] = (m & 0xFFFF) | (((m >> 16) & 15) << 20);
    }
    if (v == 2 && bk == nbk - 1 && t == 0) off3[(size_t)3 * M] = Etot;
}

// ---- gather: T[v][d][b][:] += coef*h[src]; h row-swizzled, T written row-swizzled ----
struct GatherArgs {
    const int* off3;
    const int* packed3;
    const float* coef[3];     // [R][4]
    const _Float16* h[3];     // [N][128] swizzled
    _Float16* T;              // [N][4][128] swizzled per node
    int N; size_t Tvs;
};

__global__ __launch_bounds__(256) void gather3(GatherArgs g) {
    int v = blockIdx.y;
    int node = (blockIdx.x << 2) | (threadIdx.x >> 6);
    if (node >= g.N) return;
    int lane = threadIdx.x & 63;
    const int* off = g.off3 + (size_t)v * g.N;
    const float* coef = g.coef[v];
    const _Float16* h = g.h[v];
    _Float16* T = g.T + (size_t)v * g.Tvs;

    int i  = __builtin_amdgcn_readfirstlane(off[node]);
    int e1 = __builtin_amdgcn_readfirstlane(off[node + 1]);
    float acc[8] = {};   // [b][2]

    for (; i + 3 < e1; i += 4) {
        int p0 = __builtin_amdgcn_readfirstlane(g.packed3[i]);
        int p1 = __builtin_amdgcn_readfirstlane(g.packed3[i + 1]);
        int p2 = __builtin_amdgcn_readfirstlane(g.packed3[i + 2]);
        int p3 = __builtin_amdgcn_readfirstlane(g.packed3[i + 3]);
        int s0 = p0 & 0xFFFFF, r0 = p0 >> 20;
        int s1 = p1 & 0xFFFFF, r1 = p1 >> 20;
        int s2 = p2 & 0xFFFFF, r2 = p2 >> 20;
        int s3 = p3 & 0xFFFFF, r3 = p3 >> 20;
        uint32_t q0 = ((const uint32_t*)(h + (size_t)s0 * 128))[lane ^ ((s0 & 7) << 2)];
        uint32_t q1 = ((const uint32_t*)(h + (size_t)s1 * 128))[lane ^ ((s1 & 7) << 2)];
        uint32_t q2 = ((const uint32_t*)(h + (size_t)s2 * 128))[lane ^ ((s2 & 7) << 2)];
        uint32_t q3 = ((const uint32_t*)(h + (size_t)s3 * 128))[lane ^ ((s3 & 7) << 2)];
        float4 c0 = *(const float4*)(coef + (size_t)r0 * 4);
        float4 c1 = *(const float4*)(coef + (size_t)r1 * 4);
        float4 c2 = *(const float4*)(coef + (size_t)r2 * 4);
        float4 c3 = *(const float4*)(coef + (size_t)r3 * 4);
        f16x2 u0 = __builtin_bit_cast(f16x2, q0);
        f16x2 u1 = __builtin_bit_cast(f16x2, q1);
        f16x2 u2 = __builtin_bit_cast(f16x2, q2);
        f16x2 u3 = __builtin_bit_cast(f16x2, q3);
        float lo0 = (float)u0[0], hi0 = (float)u0[1];
        float lo1 = (float)u1[0], hi1 = (float)u1[1];
        float lo2 = (float)u2[0], hi2 = (float)u2[1];
        float lo3 = (float)u3[0], hi3 = (float)u3[1];
        acc[0] += c0.x * lo0 + c1.x * lo1 + c2.x * lo2 + c3.x * lo3;
        acc[1] += c0.x * hi0 + c1.x * hi1 + c2.x * hi2 + c3.x * hi3;
        acc[2] += c0.y * lo0 + c1.y * lo1 + c2.y * lo2 + c3.y * lo3;
        acc[3] += c0.y * hi0 + c1.y * hi1 + c2.y * hi2 + c3.y * hi3;
        acc[4] += c0.z * lo0 + c1.z * lo1 + c2.z * lo2 + c3.z * lo3;
        acc[5] += c0.z * hi0 + c1.z * hi1 + c2.z * hi2 + c3.z * hi3;
        acc[6] += c0.w * lo0 + c1.w * lo1 + c2.w * lo2 + c3.w * lo3;
        acc[7] += c0.w * hi0 + c1.w * hi1 + c2.w * hi2 + c3.w * hi3;
    }
    for (; i < e1; ++i) {
        int p0 = __builtin_amdgcn_readfirstlane(g.packed3[i]);
        int s0 = p0 & 0xFFFFF, r0 = p0 >> 20;
        uint32_t q0 = ((const uint32_t*)(h + (size_t)s0 * 128))[lane ^ ((s0 & 7) << 2)];
        float4 c0 = *(const float4*)(coef + (size_t)r0 * 4);
        f16x2 u0 = __builtin_bit_cast(f16x2, q0);
        float lo0 = (float)u0[0], hi0 = (float)u0[1];
        acc[0] += c0.x * lo0;  acc[1] += c0.x * hi0;
        acc[2] += c0.y * lo0;  acc[3] += c0.y * hi0;
        acc[4] += c0.z * lo0;  acc[5] += c0.z * hi0;
        acc[6] += c0.w * lo0;  acc[7] += c0.w * hi0;
    }
    int cs = (2 * lane) ^ ((node & 7) << 3);
    _Float16* tb = T + (size_t)node * 512 + cs;
    for (int b = 0; b < 4; ++b) {
        f16x2 o; o[0] = (_Float16)acc[2 * b]; o[1] = (_Float16)acc[2 * b + 1];
        *(f16x2*)(tb + b * 128) = o;
    }
}

// ---- layer GEMM: out = [T | h] @ BT^T + bias (+relu), K=640, BM=64 ----
struct GemmArgs {
    const _Float16* T;        // base; +v*Tvs (swizzled)
    const _Float16* hin[3];   // swizzled
    const _Float16* WT[3];    // [128][640] swizzled per 128-chunk
    const float* bias[3];
    _Float16* hout;           // base; +v*hovs (written swizzled)
    int M; int relu; size_t Tvs; size_t hovs;
};

__global__ __launch_bounds__(512) void gemm_layer(GemmArgs ga) {
    __shared__ _Float16 As[64 * 128];
    __shared__ _Float16 Bs[128 * 128];
    int v = blockIdx.y;
    const _Float16* Tb  = ga.T + (size_t)v * ga.Tvs;
    const _Float16* hin = ga.hin[v];
    const _Float16* BT  = ga.WT[v];
    const float* bias   = ga.bias[v];
    _Float16* out       = ga.hout + (size_t)v * ga.hovs;
    int M = ga.M;

    int tid = threadIdx.x;
    int m0 = blockIdx.x * 64;
    int wid = tid >> 6, lane = tid & 63;
    int wr = (wid >> 2) * 32;
    int wc = (wid & 3) * 32;
    int lm = lane & 15;
    int lk = (lane >> 4) * 8;
    int xm = (lm & 7) << 3;

    f32x4 acc[2][2] = {};

    for (int kb = 0; kb < 5; ++kb) {
        const _Float16* Asrc; size_t astride;
        if (kb < 4) { Asrc = Tb + (size_t)kb * 128; astride = 512; }
        else        { Asrc = hin;                   astride = 128; }
        for (int q = 0; q < 2; ++q) {
            int li = tid + q * 512;
            int r = li >> 4;
            int c = (li & 15) << 3;
            int gr = m0 + r; if (gr >= M) gr = M - 1;
            gll16(Asrc + (size_t)gr * astride + c, As + (size_t)li * 8);
        }
        for (int q = 0; q < 4; ++q) {
            int li = tid + q * 512;
            gll16(BT + (size_t)(li >> 4) * 640 + kb * 128 + ((li & 15) << 3),
                  Bs + (size_t)li * 8);
        }
        __syncthreads();

        for (int ks = 0; ks < 4; ++ks) {
            int ac = (ks * 32 + lk) ^ xm;
            f16x8 a[2], b[2];
            for (int mi = 0; mi < 2; ++mi)
                a[mi] = *(const f16x8*)(As + (wr + mi * 16 + lm) * 128 + ac);
            for (int ni = 0; ni < 2; ++ni)
                b[ni] = *(const f16x8*)(Bs + (wc + ni * 16 + lm) * 128 + ac);
            for (int mi = 0; mi < 2; ++mi)
                for (int ni = 0; ni < 2; ++ni)
                    acc[mi][ni] = __builtin_amdgcn_mfma_f32_16x16x32_f16(a[mi], b[ni], acc[mi][ni], 0, 0, 0);
        }
        __syncthreads();
    }

    int rbase = (lane >> 4) * 4;
    for (int mi = 0; mi < 2; ++mi) {
        for (int j = 0; j < 4; ++j) {
            int gr = m0 + wr + mi * 16 + rbase + j;
            if (gr >= M) continue;
            int rs = (gr & 7) << 3;
            for (int ni = 0; ni < 2; ++ni) {
                int col = wc + ni * 16 + lm;
                float val = acc[mi][ni][j] + bias[col];
                if (ga.relu) val = fmaxf(val, 0.f);
                out[(size_t)gr * 128 + (col ^ rs)] = (_Float16)val;
            }
        }
    }
}

// ---- fusion GEMM: out_f32 = sum_kb A[kb] @ BT_chunk + bias, BM=128, unswizzled output ----
struct FusArgs {
    const _Float16* A[3];     // K-chunks, each [M][128] swizzled
    const _Float16* BT;       // [128][384] swizzled per 128-chunk
    const float* bias;
    float* out; int M;
};

__global__ __launch_bounds__(256) void gemm_fusion(FusArgs fa) {
    __shared__ _Float16 As[128 * 128];
    __shared__ _Float16 Bs[128 * 128];
    int tid = threadIdx.x;
    int m0 = blockIdx.x * 128;
    int M = fa.M;
    int wid = tid >> 6, lane = tid & 63;
    int wr = (wid >> 1) * 64;
    int wc = (wid & 1) * 64;
    int lm = lane & 15;
    int lk = (lane >> 4) * 8;
    int xm = (lm & 7) << 3;

    f32x4 acc[4][4] = {};

    for (int kb = 0; kb < 3; ++kb) {
        const _Float16* Asrc = fa.A[kb];
        for (int q = 0; q < 8; ++q) {
            int li = tid + q * 256;
            int r = li >> 4;
            int c = (li & 15) << 3;
            int gr = m0 + r; if (gr >= M) gr = M - 1;
            gll16(Asrc + (size_t)gr * 128 + c, As + (size_t)li * 8);
        }
        for (int q = 0; q < 8; ++q) {
            int li = tid + q * 256;
            gll16(fa.BT + (size_t)(li >> 4) * 384 + kb * 128 + ((li & 15) << 3),
                  Bs + (size_t)li * 8);
        }
        __syncthreads();

        for (int ks = 0; ks < 4; ++ks) {
            int ac = (ks * 32 + lk) ^ xm;
            f16x8 a[4], b[4];
            for (int mi = 0; mi < 4; ++mi)
                a[mi] = *(const f16x8*)(As + (wr + mi * 16 + lm) * 128 + ac);
            for (int ni = 0; ni < 4; ++ni)
                b[ni] = *(const f16x8*)(Bs + (wc + ni * 16 + lm) * 128 + ac);
            for (int mi = 0; mi < 4; ++mi)
                for (int ni = 0; ni < 4; ++ni)
                    acc[mi][ni] = __builtin_amdgcn_mfma_f32_16x16x32_f16(a[mi], b[ni], acc[mi][ni], 0, 0, 0);
        }
        __syncthreads();
    }

    int rbase = (lane >> 4) * 4;
    for (int mi = 0; mi < 4; ++mi) {
        for (int j = 0; j < 4; ++j) {
            int gr = m0 + wr + mi * 16 + rbase + j;
            if (gr >= M) continue;
            for (int ni = 0; ni < 4; ++ni) {
                int col = wc + ni * 16 + lm;
                fa.out[(size_t)gr * 128 + col] = acc[mi][ni][j] + fa.bias[col];
            }
        }
    }
}

// ---------------- host launch ----------------
extern "C" void kernel_launch(void* const* d_in, const int* in_sizes, int n_in,
                              void* d_out, int out_size, void* d_ws, size_t ws_size,
                              hipStream_t stream) {
    const int D = 128;
    const int M = in_sizes[0] / D;

    struct ViewIn {
        const int *src, *dst, *rel;
        const float *bases1, *coef1, *loopw1, *bias1;
        const float *bases2, *coef2, *loopw2, *bias2;
        int E;
    } V[3];
    int idx = 1;
    for (int v = 0; v < 3; ++v) {
        V[v].src    = (const int*)d_in[idx + 0];
        V[v].dst    = (const int*)d_in[idx + 1];
        V[v].rel    = (const int*)d_in[idx + 2];
        V[v].bases1 = (const float*)d_in[idx + 3];
        V[v].coef1  = (const float*)d_in[idx + 4];
        V[v].loopw1 = (const float*)d_in[idx + 5];
        V[v].bias1  = (const float*)d_in[idx + 6];
        V[v].bases2 = (const float*)d_in[idx + 7];
        V[v].coef2  = (const float*)d_in[idx + 8];
        V[v].loopw2 = (const float*)d_in[idx + 9];
        V[v].bias2  = (const float*)d_in[idx + 10];
        V[v].E      = in_sizes[idx + 0];
        idx += 11;
    }
    const float* fusion_w = (const float*)d_in[idx];
    const float* fusion_b = (const float*)d_in[idx + 1];
    int Etot = V[0].E + V[1].E + V[2].E;

    int nbk = (M + 255) >> 8;          // buckets per view (assumes M <= 65536)
    int nsc = 3 * nbk * 64;            // scan length over (view, bucket, block)

    // ---- workspace carve ----
    char* w = (char*)d_ws;
    auto alloc = [&](size_t bytes) -> char* {
        char* p = w; w += (bytes + 255) & ~(size_t)255; return p;
    };
    _Float16* nf16 = (_Float16*)alloc((size_t)M * 128 * 2);
    _Float16* wts  = (_Float16*)alloc((size_t)(6 * 81920 + 49152) * 2);
    int* hmat      = (int*)alloc((size_t)nsc * 4);
    int* smat      = (int*)alloc(((size_t)nsc + 1) * 4);
    int* bsum      = (int*)alloc(512);
    int* off3      = (int*)alloc(((size_t)3 * M + 1) * 4);
    int* mid       = (int*)alloc((size_t)Etot * 4);
    int* packed3   = (int*)alloc((size_t)Etot * 4);
    _Float16* T3   = (_Float16*)alloc((size_t)3 * M * 512 * 2);
    _Float16* h1b  = (_Float16*)alloc((size_t)3 * M * 128 * 2);
    _Float16* h2b  = (_Float16*)alloc((size_t)3 * M * 128 * 2);

    // WT[v][l]: [128][640]; fusTcat: [128][384]
    _Float16 *WT[3][2];
    for (int v = 0; v < 3; ++v)
        for (int l = 0; l < 2; ++l)
            WT[v][l] = wts + (size_t)(v * 2 + l) * 81920;
    _Float16* fusTcat = wts + 6 * 81920;

    // ---- prep descriptors ----
    PrepArgs pa;
    int t = 0;
    for (int v = 0; v < 3; ++v) {
        const float* bases[2] = { V[v].bases1, V[v].bases2 };
        const float* loopw[2] = { V[v].loopw1, V[v].loopw2 };
        for (int l = 0; l < 2; ++l) {
            for (int b = 0; b < 4; ++b) {
                pa.d[t].src = bases[l] + (size_t)b * 16384;
                pa.d[t].dst = WT[v][l] + (size_t)b * 128;
                pa.d[t].dstride = 640; ++t;
            }
            pa.d[t].src = loopw[l];
            pa.d[t].dst = WT[v][l] + 512;
            pa.d[t].dstride = 640; ++t;
        }
    }
    for (int v = 0; v < 3; ++v) {
        pa.d[t].src = fusion_w + (size_t)v * 16384;
        pa.d[t].dst = fusTcat + (size_t)v * 128;
        pa.d[t].dstride = 384; ++t;
    }
    prep_weights<<<33, 256, 0, stream>>>(pa);

    int n4 = M * D / 4;
    f32_to_f16<<<(n4 + 255) / 256, 256, 0, stream>>>((const float*)d_in[0], nf16, n4);

    // ---- CSR build (block-local counting sort) ----
    EdgeArgs ea;
    for (int v = 0; v < 3; ++v) {
        ea.src[v] = V[v].src; ea.dst[v] = V[v].dst; ea.rel[v] = V[v].rel; ea.E[v] = V[v].E;
    }
    ea.N = M;
    int nsb = (nsc + 2047) / 2048;
    bhist<<<dim3(64, 3), 256, 0, stream>>>(ea, hmat, nbk);
    scan1_kernel<<<nsb, 256, 0, stream>>>(hmat, smat, bsum, nsc);
    scan2b<<<nsb, 256, 0, stream>>>(smat, bsum, nsc, Etot);
    bscat<<<dim3(64, 3), 256, 0, stream>>>(ea, smat, mid, nbk);
    bfinal<<<dim3(nbk, 3), 256, 0, stream>>>(smat, mid, off3, packed3, M, nbk, Etot);

    int ng  = (M + 3) / 4;
    int gxL = (M + 63) / 64;
    int gxF = (M + 127) / 128;
    size_t Tvs = (size_t)M * 512;
    size_t hvs = (size_t)M * 128;
    float* outF = (float*)d_out;

    // ---- layer 1 ----
    GatherArgs g1;
    g1.off3 = off3; g1.packed3 = packed3; g1.T = T3; g1.N = M; g1.Tvs = Tvs;
    for (int v = 0; v < 3; ++v) { g1.coef[v] = V[v].coef1; g1.h[v] = nf16; }
    gather3<<<dim3(ng, 3), 256, 0, stream>>>(g1);

    GemmArgs m1;
    m1.T = T3; m1.hout = h1b; m1.M = M; m1.relu = 1; m1.Tvs = Tvs; m1.hovs = hvs;
    for (int v = 0; v < 3; ++v) { m1.hin[v] = nf16; m1.WT[v] = WT[v][0]; m1.bias[v] = V[v].bias1; }
    gemm_layer<<<dim3(gxL, 3), 512, 0, stream>>>(m1);

    // ---- layer 2 ----
    GatherArgs g2 = g1;
    for (int v = 0; v < 3; ++v) { g2.coef[v] = V[v].coef2; g2.h[v] = h1b + (size_t)v * hvs; }
    gather3<<<dim3(ng, 3), 256, 0, stream>>>(g2);

    GemmArgs m2;
    m2.T = T3; m2.hout = h2b; m2.M = M; m2.relu = 0; m2.Tvs = Tvs; m2.hovs = hvs;
    for (int v = 0; v < 3; ++v) { m2.hin[v] = h1b + (size_t)v * hvs; m2.WT[v] = WT[v][1]; m2.bias[v] = V[v].bias2; }
    gemm_layer<<<dim3(gxL, 3), 512, 0, stream>>>(m2);

    // ---- fusion ----
    FusArgs fa;
    for (int v = 0; v < 3; ++v) fa.A[v] = h2b + (size_t)v * hvs;
    fa.BT = fusTcat; fa.bias = fusion_b; fa.out = outF; fa.M = M;
    gemm_fusion<<<gxF, 256, 0, stream>>>(fa);
}